// Round 10
// baseline (26.665 us; speedup 1.0000x reference)
//
#include <hip/hip_runtime.h>

#define N_IN   4096
#define N_NPB  64
#define COLS   16384
#define BATCH  128

typedef unsigned int       uint;
typedef unsigned short     ushort;
typedef __attribute__((ext_vector_type(2))) _Float16 h2;

// ---------------------------------------------------------------------------
// ws layout:
//   [0,      1 MiB)  xT4 : f16, slice-major [32 slices][4096 rows][4 batches]
//   [1 MiB,  5 MiB)  pku : uint [64 k][16384 c] = (row << 16) | f16bits(w_eff)
// ---------------------------------------------------------------------------

static __device__ __forceinline__ ushort f16bits(float v) {
  return __builtin_bit_cast(ushort, (_Float16)v);
}

// keepmask + pack for k-group [KB, KB+16): keep iff no later k' duplicates.
template <int KB>
static __device__ __forceinline__ void keep_pk(
    const int* __restrict__ ip, const float* __restrict__ wp,
    uint* __restrict__ pkout) {
  int  g[16];
  uint m[16];
#pragma unroll
  for (int j = 0; j < 16; ++j) { g[j] = ip[(KB + j) * COLS]; m[j] = 0xffffffffu; }
#pragma unroll
  for (int j = 0; j < 16; ++j)
#pragma unroll
    for (int kp = j + 1; kp < 16; ++kp)
      m[j] = min(m[j], (uint)(g[j] ^ g[kp]));
#pragma unroll 4
  for (int kp = KB + 16; kp < 64; ++kp) {
    const int vk = ip[kp * COLS];
#pragma unroll
    for (int j = 0; j < 16; ++j) m[j] = min(m[j], (uint)(g[j] ^ vk));
  }
#pragma unroll
  for (int j = 0; j < 16; ++j) {
    const float wv = (m[j] != 0u) ? wp[(KB + j) * COLS] : 0.0f;
    pkout[(KB + j) * COLS] = ((uint)g[j] << 16) | (uint)f16bits(wv);
  }
}

// Fused prep: blocks [0,512) transpose x -> slice-major f16 xT4;
// blocks [512,768) keepmask + pku pack.
__global__ __launch_bounds__(256, 4) void prep_kernel(
    const float* __restrict__ x, const int* __restrict__ idx,
    const float* __restrict__ w, ushort* __restrict__ xT4,
    uint* __restrict__ pku) {
  const int bid = blockIdx.x;
  const int tid = threadIdx.x;
  if (bid < 512) {
    __shared__ float tile[32][33];
    const int i0 = (bid & 127) * 32;
    const int b0 = (bid >> 7) * 32;
    const int tx = tid & 31;
    const int ty = tid >> 5;    // 0..7
#pragma unroll
    for (int j = 0; j < 32; j += 8)
      tile[ty + j][tx] = x[(b0 + ty + j) * N_IN + i0 + tx];
    __syncthreads();
#pragma unroll
    for (int j = 0; j < 32; j += 8) {
      const int b = b0 + tx, i = i0 + ty + j;
      // xT4[b>>2][i][b&3]
      xT4[((b >> 2) << 14) + (i << 2) + (b & 3)] = f16bits(tile[tx][ty + j]);
    }
  } else {
    const int kg = __builtin_amdgcn_readfirstlane(tid >> 6);  // wave-uniform
    const int c  = (bid - 512) * 64 + (tid & 63);
    if      (kg == 0) keep_pk<0 >(idx + c, w + c, pku + c);
    else if (kg == 1) keep_pk<16>(idx + c, w + c, pku + c);
    else if (kg == 2) keep_pk<32>(idx + c, w + c, pku + c);
    else              keep_pk<48>(idx + c, w + c, pku + c);
  }
}

// ---------------------------------------------------------------------------
// Main: out[b,c] = sum_k w_eff[k,c] * x[b, row(k,c)], gathered from LDS.
// Grid 1024: r = bid & 31 (col-range of 512 cols), s = bid >> 5 (4 batches).
// XCD pinning: all blocks of col-range r have bid%8 == r%8, so that range's
// pku lines live in one XCD's L2 across its 32 slice-blocks.
// Block: stage xT4[s] (4096 rows x 4 batches = 32 KB) into LDS; one column
// per thread; k-loop = global pk dword (coalesced, L2-hot) + ds_read_b64
// (8 B = the row's 4 batches) + 2 v_pk_fma_f16. No big VGPR arrays ->
// deep pipelining; 32 KB LDS -> 4 blocks/CU = 32 waves/CU.
// ---------------------------------------------------------------------------
__global__ __launch_bounds__(512, 8) void gather_kernel(
    const uint* __restrict__ pku, const ushort* __restrict__ xT4,
    float* __restrict__ out) {
  __shared__ __align__(16) ushort xls[4096 * 4];   // 32 KB: [row][4 batches]

  const int tid  = threadIdx.x;
  const int bid  = blockIdx.x;
  const int r    = bid & 31;
  const int s    = bid >> 5;
  const int wave = tid >> 6;
  const int lane = tid & 63;
  const int c    = r * 512 + wave * 64 + lane;   // this lane's column

  // Stage slice s: 32 KB via global_load_lds (16 B/lane; dest wave-uniform).
  {
    const ushort* src = xT4 + (s << 14);
#pragma unroll
    for (int t = 0; t < 4; ++t) {
      const int ub = (t * 8 + wave) * 512;       // ushort base, wave-uniform
      __builtin_amdgcn_global_load_lds(
          (const __attribute__((address_space(1))) void*)(src + ub + lane * 8),
          (__attribute__((address_space(3))) void*)(xls + ub), 16, 0, 0);
    }
  }
  __syncthreads();   // drains vmcnt incl. global_load_lds

  // Gather-accumulate. Two independent chains (even/odd k).
  const uint* pc = pku + c;
  const char* xb = (const char*)xls;
  h2 a0 = (h2)0.0f, a1 = (h2)0.0f, a2 = (h2)0.0f, a3 = (h2)0.0f;
#pragma unroll
  for (int k = 0; k < N_NPB; k += 2) {
    const uint e0 = pc[k * COLS];                 // coalesced dword, L2-hot
    const uint e1 = pc[(k + 1) * COLS];
    const uint o0 = (e0 >> 16) << 3;              // row * 8 B
    const uint o1 = (e1 >> 16) << 3;
    const uint w0 = e0 & 0xffffu, w1 = e1 & 0xffffu;
    const h2 wh0 = __builtin_bit_cast(h2, (w0 << 16) | w0);
    const h2 wh1 = __builtin_bit_cast(h2, (w1 << 16) | w1);
    const uint2 u0 = *(const uint2*)(xb + o0);    // ds_read_b64: 4 batches
    const uint2 u1 = *(const uint2*)(xb + o1);
    a0 += __builtin_bit_cast(h2, u0.x) * wh0;     // v_pk_fma_f16
    a1 += __builtin_bit_cast(h2, u0.y) * wh0;
    a2 += __builtin_bit_cast(h2, u1.x) * wh1;
    a3 += __builtin_bit_cast(h2, u1.y) * wh1;
  }

  // Direct coalesced stores: 4 batches x 256 B-consecutive columns per wave.
  out[(s * 4 + 0) * COLS + c] = (float)a0.x + (float)a2.x;
  out[(s * 4 + 1) * COLS + c] = (float)a0.y + (float)a2.y;
  out[(s * 4 + 2) * COLS + c] = (float)a1.x + (float)a3.x;
  out[(s * 4 + 3) * COLS + c] = (float)a1.y + (float)a3.y;
}

extern "C" void kernel_launch(void* const* d_in, const int* in_sizes, int n_in,
                              void* d_out, int out_size, void* d_ws, size_t ws_size,
                              hipStream_t stream) {
  const float* x   = (const float*)d_in[0];
  const float* w   = (const float*)d_in[1];
  const int*   idx = (const int*)d_in[2];
  float* out = (float*)d_out;

  char* ws = (char*)d_ws;
  ushort* xT4 = (ushort*)(ws);
  uint*   pku = (uint*)(ws + (1u << 20));

  hipLaunchKernelGGL(prep_kernel, dim3(768), dim3(256), 0, stream,
                     x, idx, w, xT4, pku);
  hipLaunchKernelGGL(gather_kernel, dim3(1024), dim3(512), 0, stream,
                     pku, xT4, out);
}